// Round 10
// baseline (325.188 us; speedup 1.0000x reference)
//
#include <hip/hip_runtime.h>

#define FEAT 128

typedef __attribute__((ext_vector_type(8))) _Float16 f16x8;
typedef __attribute__((ext_vector_type(2))) _Float16 f16x2;
typedef __attribute__((ext_vector_type(4))) float f32x4;

static __device__ __forceinline__ int wave_incl_scan(int v, int lane) {
#pragma unroll
    for (int off = 1; off < 64; off <<= 1) {
        int u = __shfl_up(v, off, 64);
        if (lane >= off) v += u;
    }
    return v;
}

// ---------------------------------------------------------------------------
// Prep: per-dst histogram (atomicAdd return = edge rank -> erank, giving an
// atomic-free scatter later) + weight/bias converts. SLABS removed (slab
// L2-phasing proven useless r1/r4; kills the per-edge 32-bit division).
// Feat conversion removed entirely: fused0 reads f32 feats directly.
// ---------------------------------------------------------------------------

__global__ void prep_kernel(const int* __restrict__ src, const int* __restrict__ dst,
                            int* __restrict__ deg, int* __restrict__ erank, int E,
                            const float* __restrict__ tw, const float* __restrict__ pw,
                            const float* __restrict__ tb, const float* __restrict__ pb,
                            _Float16* __restrict__ wt, _Float16* __restrict__ wp,
                            float* __restrict__ bsum, int wn, int nbias,
                            int hb) {
    int bid = blockIdx.x;
    if (bid < hb) {
        int e = bid * 256 + threadIdx.x;
        if (e < E) {
            erank[e] = atomicAdd(&deg[dst[e]], 1);
        }
    } else {
        int i = (bid - hb) * 256 + threadIdx.x;
        if (i < wn) { wt[i] = (_Float16)tw[i]; wp[i] = (_Float16)pw[i]; }
        if (i < nbias) bsum[i] = tb[i] + pb[i];
    }
}

// ---------------------------------------------------------------------------
// 2-dispatch scan over the N-entry degree array (scan3 folded into
// consumers: they add boff[idx>>10]). Round-5 lesson: NO single-dispatch
// device-scope-spin scan (cost 103 us).
// ---------------------------------------------------------------------------

__global__ __launch_bounds__(1024) void scan1_kernel(const int* __restrict__ deg,
                                                     int* __restrict__ row_ptr,
                                                     int* __restrict__ bsum, int N) {
    int i = blockIdx.x * 1024 + threadIdx.x;
    int lane = threadIdx.x & 63;
    int w = threadIdx.x >> 6;
    int v = (i < N) ? deg[i] : 0;
    int inc = wave_incl_scan(v, lane);
    __shared__ int wsum[16];
    if (lane == 63) wsum[w] = inc;
    __syncthreads();
    if (w == 0) {
        int s = (lane < 16) ? wsum[lane] : 0;
        int si = wave_incl_scan(s, lane);
        if (lane < 16) wsum[lane] = si - s;
    }
    __syncthreads();
    int exc = inc - v + wsum[w];
    if (i < N) row_ptr[i] = exc;
    if (threadIdx.x == 1023) bsum[blockIdx.x] = exc + v;
}

// boff[tid] for tid<=nb; sentinel row_ptr[N] pre-compensated so consumers
// can uniformly compute row_ptr[idx] + boff[idx>>10].
__global__ __launch_bounds__(1024) void scan2_kernel(const int* __restrict__ bsum,
                                                     int* __restrict__ boff,
                                                     int* __restrict__ row_ptr,
                                                     int nb, int N, int E) {
    int tid = threadIdx.x;
    int lane = tid & 63;
    int w = tid >> 6;
    int v = (tid < nb) ? bsum[tid] : 0;
    int inc = wave_incl_scan(v, lane);
    __shared__ int wsum[16];
    if (lane == 63) wsum[w] = inc;
    __syncthreads();
    if (w == 0) {
        int s = (lane < 16) ? wsum[lane] : 0;
        int si = wave_incl_scan(s, lane);
        if (lane < 16) wsum[lane] = si - s;
    }
    __syncthreads();
    int b = inc - v + wsum[w];
    if (tid <= nb) boff[tid] = b;
    if (tid == (N >> 10)) row_ptr[N] = E - b;   // + boff[N>>10] == E
}

// ---------------------------------------------------------------------------
// Layer-0 GEMM (reads f32 feats directly, converts in-register -- same
// rounding point as the old x16 path, 38 MB less traffic) fused with the
// atomic-free CSR scatter. t = x @ Wt.T, q = x @ Wp.T - t + (tb+pb).
// C/D layout: col = lane&15, row = (lane>>4)*4+reg.
// ---------------------------------------------------------------------------

__global__ __launch_bounds__(256) void fused0_kernel(
        const float* __restrict__ xf,
        const _Float16* __restrict__ wt, const _Float16* __restrict__ wp,
        const float* __restrict__ bias,
        _Float16* __restrict__ t16, _Float16* __restrict__ q16, int M, int gb,
        const int* __restrict__ src, const int* __restrict__ dst,
        const int* __restrict__ row_ptr, const int* __restrict__ boff,
        const int* __restrict__ erank,
        int* __restrict__ esrc, int E) {
    if ((int)blockIdx.x < gb) {
        int lane = threadIdx.x & 63;
        int l16 = lane & 15;
        int quad = lane >> 4;
        int cn0 = (threadIdx.x >> 6) * 32;

        f16x8 bt[2][4], bp[2][4];
        float biasv[2];
#pragma unroll
        for (int ct = 0; ct < 2; ++ct) {
            int col = cn0 + ct * 16 + l16;
            biasv[ct] = bias[col];
#pragma unroll
            for (int kk = 0; kk < 4; ++kk) {
                int k = kk * 32 + quad * 8;
                bt[ct][kk] = *(const f16x8*)(wt + (size_t)col * FEAT + k);
                bp[ct][kk] = *(const f16x8*)(wp + (size_t)col * FEAT + k);
            }
        }

        int rbase0 = blockIdx.x * 128;
#pragma unroll 1
        for (int rs = 0; rs < 8; ++rs) {
            int rbase = rbase0 + rs * 16;
            int row = rbase + l16;
            int rowc = (row < M) ? row : (M - 1);
            f16x8 a[4];
#pragma unroll
            for (int kk = 0; kk < 4; ++kk) {
                const float4* p = (const float4*)(xf + (size_t)rowc * FEAT + kk * 32 + quad * 8);
                float4 v0 = p[0], v1 = p[1];
                f16x8 aa;
                aa[0] = (_Float16)v0.x; aa[1] = (_Float16)v0.y;
                aa[2] = (_Float16)v0.z; aa[3] = (_Float16)v0.w;
                aa[4] = (_Float16)v1.x; aa[5] = (_Float16)v1.y;
                aa[6] = (_Float16)v1.z; aa[7] = (_Float16)v1.w;
                a[kk] = aa;
            }

            f32x4 accT[2] = {{0.f, 0.f, 0.f, 0.f}, {0.f, 0.f, 0.f, 0.f}};
            f32x4 accP[2] = {{0.f, 0.f, 0.f, 0.f}, {0.f, 0.f, 0.f, 0.f}};
#pragma unroll
            for (int kk = 0; kk < 4; ++kk) {
#pragma unroll
                for (int ct = 0; ct < 2; ++ct) {
                    accT[ct] = __builtin_amdgcn_mfma_f32_16x16x32_f16(a[kk], bt[ct][kk], accT[ct], 0, 0, 0);
                    accP[ct] = __builtin_amdgcn_mfma_f32_16x16x32_f16(a[kk], bp[ct][kk], accP[ct], 0, 0, 0);
                }
            }
#pragma unroll
            for (int ct = 0; ct < 2; ++ct) {
                int col = cn0 + ct * 16 + l16;
#pragma unroll
                for (int r = 0; r < 4; ++r) {
                    int ro = rbase + quad * 4 + r;
                    if (ro < M) {
                        t16[(size_t)ro * FEAT + col] = (_Float16)accT[ct][r];
                        q16[(size_t)ro * FEAT + col] =
                            (_Float16)(accP[ct][r] - accT[ct][r] + biasv[ct]);
                    }
                }
            }
        }
    } else {
        int e = (blockIdx.x - gb) * 256 + threadIdx.x;
        if (e < E) {
            int key = dst[e];
            esrc[row_ptr[key] + boff[key >> 10] + erank[e]] = src[e];
        }
    }
}

// ---------------------------------------------------------------------------
// Gather-max core (round-1 verified; ~27 us/layer standalone, shown
// insensitive to issue count r1, pipeline depth r3, residency r4, wave
// mapping r8/r9 -- treat as at its throughput ceiling, do not restructure).
// ---------------------------------------------------------------------------

static __device__ __forceinline__ f16x8 vmax8(f16x8 a, f16x8 b) {
#pragma unroll
    for (int i = 0; i < 8; ++i) a[i] = (a[i] > b[i]) ? a[i] : b[i];
    return a;
}

static __device__ __forceinline__ f16x8 shfl_xor8(f16x8 v, int m) {
    union { f16x8 h; int i[4]; } u, r;
    u.h = v;
#pragma unroll
    for (int d = 0; d < 4; ++d) r.i[d] = __shfl_xor(u.i[d], m, 64);
    return r.h;
}

static __device__ __forceinline__ f16x8 gather_max(
        const _Float16* __restrict__ t16, const int* __restrict__ esrc,
        int beg, int cnt, int lane, int g, int c) {
    const _Float16 NEGINF = (_Float16)(-65504.0f);
    f16x8 m0, m1;
#pragma unroll
    for (int i = 0; i < 8; ++i) { m0[i] = NEGINF; m1[i] = NEGINF; }

    for (int cb = 0; cb < cnt; cb += 64) {
        int lim = cnt - cb; if (lim > 64) lim = 64;
        int a = beg + cb + (lane < lim ? lane : 0);
        int myidx = esrc[a];                    // one coalesced index load
        for (int base = 0; base < lim; base += 8) {
            int e0 = base + g;     if (e0 >= lim) e0 = 0;
            int e1 = base + 4 + g; if (e1 >= lim) e1 = 0;
            int i0 = __shfl(myidx, e0, 64);
            int i1 = __shfl(myidx, e1, 64);
            f16x8 v0 = *(const f16x8*)(t16 + (size_t)i0 * FEAT + c * 8);
            f16x8 v1 = *(const f16x8*)(t16 + (size_t)i1 * FEAT + c * 8);
            m0 = vmax8(m0, v0);
            m1 = vmax8(m1, v1);
        }
    }

    f16x8 mm = vmax8(m0, m1);
    mm = vmax8(mm, shfl_xor8(mm, 16));
    mm = vmax8(mm, shfl_xor8(mm, 32));
    return mm;
}

// lane (g,c) owns features {c*8+2g, c*8+2g+1}: static select of dword g.
static __device__ __forceinline__ f16x2 slot_pair(f16x8 mm, int g) {
    union { f16x8 h; int i[4]; } um; um.h = mm;
    int w01 = (g & 1) ? um.i[1] : um.i[0];
    int w23 = (g & 1) ? um.i[3] : um.i[2];
    int w = (g & 2) ? w23 : w01;
    union { int i; f16x2 h; } uw; uw.i = w;
    return uw.h;
}

// ---------------------------------------------------------------------------
// Fused agg(layer l) + GEMM(layer l+1), 256 thr / 4 waves, 4 nodes serial
// per wave (round-8 verified 52.8 us config; round-9 wave-per-node @1024thr
// was WORSE, 56.7 -- occupancy was ~60% in both, so wave count is not the
// lever). x_next passes through a 4 KB XOR-swizzled LDS tile; phase 2 does
// the 16-row double-GEMM. t/q double-buffered across layers.
// ---------------------------------------------------------------------------

__global__ __launch_bounds__(256) void fusedagg_kernel(
        const _Float16* __restrict__ t16, const _Float16* __restrict__ q16,
        const int* __restrict__ row_ptr, const int* __restrict__ boff,
        const int* __restrict__ esrc,
        const _Float16* __restrict__ wt, const _Float16* __restrict__ wp,
        const float* __restrict__ bias,
        _Float16* __restrict__ tn, _Float16* __restrict__ qn, int N) {
    __shared__ _Float16 xl[16 * FEAT];
    int wv = threadIdx.x >> 6;
    int lane = threadIdx.x & 63;
    int g = lane >> 4;
    int c = lane & 15;
    int node0 = blockIdx.x * 16;

    // phase 1: each wave aggs 4 consecutive nodes
#pragma unroll 1
    for (int k = 0; k < 4; ++k) {
        int nr = wv * 4 + k;
        int node = node0 + nr;
        float o0 = 0.f, o1 = 0.f;
        if (node < N) {
            int beg = row_ptr[node] + boff[node >> 10];
            int end = row_ptr[node + 1] + boff[(node + 1) >> 10];
            f16x2 qv = *(const f16x2*)(q16 + (size_t)node * FEAT + c * 8 + g * 2);
            f16x8 mm = gather_max(t16, esrc, beg, end - beg, lane, g, c);
            f16x2 mp = slot_pair(mm, g);
            o0 = fmaxf((float)mp[0] + (float)qv[0], 0.f);
            o1 = fmaxf((float)mp[1] + (float)qv[1], 0.f);
        }
        f16x2 oh; oh[0] = (_Float16)o0; oh[1] = (_Float16)o1;
        int byteoff = (nr * 256 + c * 16 + g * 4) ^ ((nr & 7) << 4);
        *(f16x2*)((char*)xl + byteoff) = oh;
    }
    __syncthreads();

    // phase 2: 16-row x 128-col double GEMM from LDS. Wave wv owns 32 cols.
    int l16 = lane & 15;
    int quad = lane >> 4;
    int cn0 = wv * 32;
    f16x8 a[4];
#pragma unroll
    for (int kk = 0; kk < 4; ++kk) {
        int byteoff = (l16 * 256 + kk * 64 + quad * 16) ^ ((l16 & 7) << 4);
        a[kk] = *(const f16x8*)((const char*)xl + byteoff);
    }
#pragma unroll 1
    for (int ct = 0; ct < 2; ++ct) {
        int col = cn0 + ct * 16 + l16;
        float bv = bias[col];
        f16x8 fb[4];
#pragma unroll
        for (int kk = 0; kk < 4; ++kk)
            fb[kk] = *(const f16x8*)(wt + (size_t)col * FEAT + kk * 32 + quad * 8);
        f32x4 accT = {0.f, 0.f, 0.f, 0.f};
#pragma unroll
        for (int kk = 0; kk < 4; ++kk)
            accT = __builtin_amdgcn_mfma_f32_16x16x32_f16(a[kk], fb[kk], accT, 0, 0, 0);
#pragma unroll
        for (int kk = 0; kk < 4; ++kk)
            fb[kk] = *(const f16x8*)(wp + (size_t)col * FEAT + kk * 32 + quad * 8);
        f32x4 accP = {0.f, 0.f, 0.f, 0.f};
#pragma unroll
        for (int kk = 0; kk < 4; ++kk)
            accP = __builtin_amdgcn_mfma_f32_16x16x32_f16(a[kk], fb[kk], accP, 0, 0, 0);
#pragma unroll
        for (int r = 0; r < 4; ++r) {
            int ro = node0 + quad * 4 + r;
            if (ro < N) {
                tn[(size_t)ro * FEAT + col] = (_Float16)accT[r];
                qn[(size_t)ro * FEAT + col] = (_Float16)(accP[r] - accT[r] + bv);
            }
        }
    }
}

// Final-layer agg: full-occupancy standalone, writes fp32 d_out.
__global__ __launch_bounds__(256) void agg_kernel(
        const _Float16* __restrict__ t16, const _Float16* __restrict__ q16,
        const int* __restrict__ row_ptr, const int* __restrict__ boff,
        const int* __restrict__ esrc,
        float* __restrict__ outf, int N) {
    int wv = threadIdx.x >> 6;
    int lane = threadIdx.x & 63;
    int node = blockIdx.x * 4 + wv;
    if (node >= N) return;

    int g = lane >> 4;
    int c = lane & 15;

    int beg = row_ptr[node] + boff[node >> 10];
    int end = row_ptr[node + 1] + boff[(node + 1) >> 10];

    f16x2 qv = *(const f16x2*)(q16 + (size_t)node * FEAT + c * 8 + g * 2);
    f16x8 mm = gather_max(t16, esrc, beg, end - beg, lane, g, c);
    f16x2 mp = slot_pair(mm, g);

    float o0 = fmaxf((float)mp[0] + (float)qv[0], 0.f);
    float o1 = fmaxf((float)mp[1] + (float)qv[1], 0.f);
    float2 ov = make_float2(o0, o1);
    *(float2*)(outf + (size_t)node * FEAT + c * 8 + g * 2) = ov;
}

// ---------------------------------------------------------------------------

extern "C" void kernel_launch(void* const* d_in, const int* in_sizes, int n_in,
                              void* d_out, int out_size, void* d_ws, size_t ws_size,
                              hipStream_t stream) {
    const float* feats   = (const float*)d_in[0];
    const int*   src     = (const int*)d_in[1];
    const int*   dst     = (const int*)d_in[2];
    const float* theta_w = (const float*)d_in[3];
    const float* theta_b = (const float*)d_in[4];
    const float* phi_w   = (const float*)d_in[5];
    const float* phi_b   = (const float*)d_in[6];

    const int N = in_sizes[0] / FEAT;
    const int E = in_sizes[1];
    const int L = in_sizes[3] / (FEAT * FEAT);

    char* ws = (char*)d_ws;
    size_t off = 0;
    auto alloc = [&](size_t bytes) -> void* {
        void* ptr = ws + off;
        off = (off + bytes + 255) & ~(size_t)255;
        return ptr;
    };
    _Float16* tbuf[2];
    _Float16* qbuf[2];
    tbuf[0] = (_Float16*)alloc((size_t)N * FEAT * 2);
    tbuf[1] = (_Float16*)alloc((size_t)N * FEAT * 2);
    qbuf[0] = (_Float16*)alloc((size_t)N * FEAT * 2);
    qbuf[1] = (_Float16*)alloc((size_t)N * FEAT * 2);
    _Float16* wt16 = (_Float16*)alloc((size_t)L * FEAT * FEAT * 2);
    _Float16* wp16 = (_Float16*)alloc((size_t)L * FEAT * FEAT * 2);
    float* bsum_b = (float*)alloc((size_t)L * FEAT * sizeof(float));
    int* deg      = (int*)alloc((size_t)N * sizeof(int));
    int* row_ptr  = (int*)alloc((size_t)(N + 1) * sizeof(int));
    int* erank    = (int*)alloc((size_t)E * sizeof(int));
    int* esrc     = (int*)alloc((size_t)E * sizeof(int));
    int* bsum     = (int*)alloc(2048 * sizeof(int));
    int* boff     = (int*)alloc(2048 * sizeof(int));
    (void)ws_size;

    hipMemsetAsync(deg, 0, (size_t)N * sizeof(int), stream);

    int eb = (E + 255) / 256;
    int wn = L * FEAT * FEAT;
    int wb = (wn + 255) / 256;
    prep_kernel<<<eb + wb, 256, 0, stream>>>(
        src, dst, deg, erank, E,
        theta_w, phi_w, theta_b, phi_b, wt16, wp16, bsum_b, wn, L * FEAT,
        eb);

    int nb = (N + 1023) >> 10;
    scan1_kernel<<<nb, 1024, 0, stream>>>(deg, row_ptr, bsum, N);
    scan2_kernel<<<1, 1024, 0, stream>>>(bsum, boff, row_ptr, nb, N, E);

    int gb = (N + 127) / 128;
    fused0_kernel<<<gb + eb, 256, 0, stream>>>(
        feats, wt16, wp16, bsum_b, tbuf[0], qbuf[0], N, gb,
        src, dst, row_ptr, boff, erank, esrc, E);

    int fb = (N + 15) / 16;   // fusedagg: 16 nodes/block (r8 config)
    for (int l = 0; l + 1 < L; ++l) {
        fusedagg_kernel<<<fb, 256, 0, stream>>>(
            tbuf[l & 1], qbuf[l & 1], row_ptr, boff, esrc,
            wt16 + (size_t)(l + 1) * FEAT * FEAT,
            wp16 + (size_t)(l + 1) * FEAT * FEAT,
            bsum_b + (size_t)(l + 1) * FEAT,
            tbuf[(l + 1) & 1], qbuf[(l + 1) & 1], N);
    }

    int ab = (N + 3) / 4;
    agg_kernel<<<ab, 256, 0, stream>>>(
        tbuf[(L - 1) & 1], qbuf[(L - 1) & 1], row_ptr, boff, esrc,
        (float*)d_out, N);
}

// Round 12
// 310.964 us; speedup vs baseline: 1.0457x; 1.0457x over previous
//
#include <hip/hip_runtime.h>

#define FEAT 128
#define SLABS 4

typedef __attribute__((ext_vector_type(8))) _Float16 f16x8;
typedef __attribute__((ext_vector_type(2))) _Float16 f16x2;
typedef __attribute__((ext_vector_type(4))) float f32x4;

static __device__ __forceinline__ int wave_incl_scan(int v, int lane) {
#pragma unroll
    for (int off = 1; off < 64; off <<= 1) {
        int u = __shfl_up(v, off, 64);
        if (lane >= off) v += u;
    }
    return v;
}

// ---------------------------------------------------------------------------
// Prep: histogram over (dst,slab) keys + weight/bias/feat converts, one
// dispatch partitioned by blockIdx. atomicAdd return = edge rank in bucket
// -> erank (atomic-free scatter later). SLABS=4 kept: r10 showed removing
// the slab bucketing costs gather locality (fusedagg +2 us each) and 4x
// histogram contention -- net -14 us total.
// ---------------------------------------------------------------------------

__global__ void prep_kernel(const int* __restrict__ src, const int* __restrict__ dst,
                            int* __restrict__ deg4, int* __restrict__ erank,
                            int E, int slab_size,
                            const float* __restrict__ tw, const float* __restrict__ pw,
                            const float* __restrict__ tb, const float* __restrict__ pb,
                            _Float16* __restrict__ wt, _Float16* __restrict__ wp,
                            float* __restrict__ bsum, int wn, int nbias,
                            const float* __restrict__ x, _Float16* __restrict__ x16, int xn4,
                            int hb, int wb) {
    int bid = blockIdx.x;
    if (bid < hb) {
        int e = bid * 256 + threadIdx.x;
        if (e < E) {
            int sl = src[e] / slab_size;
            erank[e] = atomicAdd(&deg4[dst[e] * SLABS + sl], 1);
        }
    } else if (bid < hb + wb) {
        int i = (bid - hb) * 256 + threadIdx.x;
        if (i < wn) { wt[i] = (_Float16)tw[i]; wp[i] = (_Float16)pw[i]; }
        if (i < nbias) bsum[i] = tb[i] + pb[i];
    } else {
        int i = (bid - hb - wb) * 256 + threadIdx.x;
        if (i < xn4) {
            float4 v = ((const float4*)x)[i];
            f16x2 a, b;
            a[0] = (_Float16)v.x; a[1] = (_Float16)v.y;
            b[0] = (_Float16)v.z; b[1] = (_Float16)v.w;
            ((f16x2*)x16)[i * 2] = a;
            ((f16x2*)x16)[i * 2 + 1] = b;
        }
    }
}

// ---------------------------------------------------------------------------
// 2-dispatch scan (scan3 folded into consumers: they add boff[idx>>10]).
// Round-5 lesson: NO single-dispatch device-scope-spin scan (cost 103 us).
// ---------------------------------------------------------------------------

__global__ __launch_bounds__(1024) void scan1_kernel(const int* __restrict__ deg,
                                                     int* __restrict__ row_ptr,
                                                     int* __restrict__ bsum, int N4) {
    int i = blockIdx.x * 1024 + threadIdx.x;
    int lane = threadIdx.x & 63;
    int w = threadIdx.x >> 6;
    int v = (i < N4) ? deg[i] : 0;
    int inc = wave_incl_scan(v, lane);
    __shared__ int wsum[16];
    if (lane == 63) wsum[w] = inc;
    __syncthreads();
    if (w == 0) {
        int s = (lane < 16) ? wsum[lane] : 0;
        int si = wave_incl_scan(s, lane);
        if (lane < 16) wsum[lane] = si - s;
    }
    __syncthreads();
    int exc = inc - v + wsum[w];
    if (i < N4) row_ptr[i] = exc;
    if (threadIdx.x == 1023) bsum[blockIdx.x] = exc + v;
}

// boff[tid] for tid<=nb; sentinel row_ptr[N4] pre-compensated so that
// consumers can uniformly compute row_ptr[idx] + boff[idx>>10].
__global__ __launch_bounds__(1024) void scan2_kernel(const int* __restrict__ bsum,
                                                     int* __restrict__ boff,
                                                     int* __restrict__ row_ptr,
                                                     int nb, int N4, int E) {
    int tid = threadIdx.x;
    int lane = tid & 63;
    int w = tid >> 6;
    int v = (tid < nb) ? bsum[tid] : 0;
    int inc = wave_incl_scan(v, lane);
    __shared__ int wsum[16];
    if (lane == 63) wsum[w] = inc;
    __syncthreads();
    if (w == 0) {
        int s = (lane < 16) ? wsum[lane] : 0;
        int si = wave_incl_scan(s, lane);
        if (lane < 16) wsum[lane] = si - s;
    }
    __syncthreads();
    int b = inc - v + wsum[w];
    if (tid <= nb) boff[tid] = b;
    if (tid == (N4 >> 10)) row_ptr[N4] = E - b;   // + boff[N4>>10] == E
}

// ---------------------------------------------------------------------------
// Fused MFMA GEMM body (verified): t = x @ Wt.T, q = x @ Wp.T - t + (tb+pb).
// C/D layout: col = lane&15, row = (lane>>4)*4+reg.
// ---------------------------------------------------------------------------

static __device__ __forceinline__ void gemm_body(
        int bx, int nslab,
        const _Float16* __restrict__ x16,
        const _Float16* __restrict__ wt, const _Float16* __restrict__ wp,
        const float* __restrict__ bias,
        _Float16* __restrict__ t16, _Float16* __restrict__ q16, int M) {
    int lane = threadIdx.x & 63;
    int l16 = lane & 15;
    int quad = lane >> 4;
    int cn0 = (threadIdx.x >> 6) * 32;

    f16x8 bt[2][4], bp[2][4];
    float biasv[2];
#pragma unroll
    for (int ct = 0; ct < 2; ++ct) {
        int col = cn0 + ct * 16 + l16;
        biasv[ct] = bias[col];
#pragma unroll
        for (int kk = 0; kk < 4; ++kk) {
            int k = kk * 32 + quad * 8;
            bt[ct][kk] = *(const f16x8*)(wt + (size_t)col * FEAT + k);
            bp[ct][kk] = *(const f16x8*)(wp + (size_t)col * FEAT + k);
        }
    }

    int rbase0 = bx * (nslab * 16);
#pragma unroll 1
    for (int rs = 0; rs < nslab; ++rs) {
        int rbase = rbase0 + rs * 16;
        int row = rbase + l16;
        int rowc = (row < M) ? row : (M - 1);
        f16x8 a[4];
#pragma unroll
        for (int kk = 0; kk < 4; ++kk)
            a[kk] = *(const f16x8*)(x16 + (size_t)rowc * FEAT + kk * 32 + quad * 8);

        f32x4 accT[2] = {{0.f, 0.f, 0.f, 0.f}, {0.f, 0.f, 0.f, 0.f}};
        f32x4 accP[2] = {{0.f, 0.f, 0.f, 0.f}, {0.f, 0.f, 0.f, 0.f}};
#pragma unroll
        for (int kk = 0; kk < 4; ++kk) {
#pragma unroll
            for (int ct = 0; ct < 2; ++ct) {
                accT[ct] = __builtin_amdgcn_mfma_f32_16x16x32_f16(a[kk], bt[ct][kk], accT[ct], 0, 0, 0);
                accP[ct] = __builtin_amdgcn_mfma_f32_16x16x32_f16(a[kk], bp[ct][kk], accP[ct], 0, 0, 0);
            }
        }
#pragma unroll
        for (int ct = 0; ct < 2; ++ct) {
            int col = cn0 + ct * 16 + l16;
#pragma unroll
            for (int r = 0; r < 4; ++r) {
                int ro = rbase + quad * 4 + r;
                if (ro < M) {
                    t16[(size_t)ro * FEAT + col] = (_Float16)accT[ct][r];
                    q16[(size_t)ro * FEAT + col] =
                        (_Float16)(accP[ct][r] - accT[ct][r] + biasv[ct]);
                }
            }
        }
    }
}

// Layer-0 GEMM fused with the atomic-free CSR scatter.
__global__ __launch_bounds__(256) void fused0_kernel(
        const _Float16* __restrict__ x16,
        const _Float16* __restrict__ wt, const _Float16* __restrict__ wp,
        const float* __restrict__ bias,
        _Float16* __restrict__ t16, _Float16* __restrict__ q16, int M, int gb,
        const int* __restrict__ src, const int* __restrict__ dst,
        const int* __restrict__ row_ptr4, const int* __restrict__ boff,
        const int* __restrict__ erank,
        int* __restrict__ esrc, int E, int slab_size) {
    if ((int)blockIdx.x < gb) {
        gemm_body(blockIdx.x, 8, x16, wt, wp, bias, t16, q16, M);
    } else {
        int e = (blockIdx.x - gb) * 256 + threadIdx.x;
        if (e < E) {
            int s = src[e];
            int key = dst[e] * SLABS + s / slab_size;
            esrc[row_ptr4[key] + boff[key >> 10] + erank[e]] = s;
        }
    }
}

// ---------------------------------------------------------------------------
// Gather-max core. vmax8 via __builtin_elementwise_max on the f16x8 vector
// (llvm.maxnum.v8f16 -> v_pk_max_f16 x4; NaN-free data so identical to the
// ternary). Gather structure itself is at its cache-line request floor
// (4x64B/edge; insensitive to issue count r1, depth r3, residency r4, wave
// mapping r8/r9) -- do not restructure.
// ---------------------------------------------------------------------------

static __device__ __forceinline__ f16x8 vmax8(f16x8 a, f16x8 b) {
    return __builtin_elementwise_max(a, b);
}

static __device__ __forceinline__ f16x8 shfl_xor8(f16x8 v, int m) {
    union { f16x8 h; int i[4]; } u, r;
    u.h = v;
#pragma unroll
    for (int d = 0; d < 4; ++d) r.i[d] = __shfl_xor(u.i[d], m, 64);
    return r.h;
}

static __device__ __forceinline__ f16x8 gather_max(
        const _Float16* __restrict__ t16, const int* __restrict__ esrc,
        int beg, int cnt, int lane, int g, int c) {
    const _Float16 NEGINF = (_Float16)(-65504.0f);
    f16x8 m0, m1;
#pragma unroll
    for (int i = 0; i < 8; ++i) { m0[i] = NEGINF; m1[i] = NEGINF; }

    for (int cb = 0; cb < cnt; cb += 64) {
        int lim = cnt - cb; if (lim > 64) lim = 64;
        int a = beg + cb + (lane < lim ? lane : 0);
        int myidx = esrc[a];                    // one coalesced index load
        for (int base = 0; base < lim; base += 8) {
            int e0 = base + g;     if (e0 >= lim) e0 = 0;
            int e1 = base + 4 + g; if (e1 >= lim) e1 = 0;
            int i0 = __shfl(myidx, e0, 64);
            int i1 = __shfl(myidx, e1, 64);
            f16x8 v0 = *(const f16x8*)(t16 + (size_t)i0 * FEAT + c * 8);
            f16x8 v1 = *(const f16x8*)(t16 + (size_t)i1 * FEAT + c * 8);
            m0 = vmax8(m0, v0);
            m1 = vmax8(m1, v1);
        }
    }

    f16x8 mm = vmax8(m0, m1);
    mm = vmax8(mm, shfl_xor8(mm, 16));
    mm = vmax8(mm, shfl_xor8(mm, 32));
    return mm;
}

// lane (g,c) owns features {c*8+2g, c*8+2g+1}: static select of dword g.
static __device__ __forceinline__ f16x2 slot_pair(f16x8 mm, int g) {
    union { f16x8 h; int i[4]; } um; um.h = mm;
    int w01 = (g & 1) ? um.i[1] : um.i[0];
    int w23 = (g & 1) ? um.i[3] : um.i[2];
    int w = (g & 2) ? w23 : w01;
    union { int i; f16x2 h; } uw; uw.i = w;
    return uw.h;
}

// ---------------------------------------------------------------------------
// Fused agg(layer l) + GEMM(layer l+1), 256 thr / 4 waves, 4 nodes serial
// per wave (round-8 verified 52.8 us config; r9 wave-per-node @1024thr was
// worse, 56.7 -- occupancy ~60% in both, wave count is not the lever).
// x_next passes through a 4 KB XOR-swizzled LDS tile; phase 2 does the
// 16-row double-GEMM. t/q double-buffered across layers.
// ---------------------------------------------------------------------------

__global__ __launch_bounds__(256) void fusedagg_kernel(
        const _Float16* __restrict__ t16, const _Float16* __restrict__ q16,
        const int* __restrict__ row_ptr4, const int* __restrict__ boff,
        const int* __restrict__ esrc,
        const _Float16* __restrict__ wt, const _Float16* __restrict__ wp,
        const float* __restrict__ bias,
        _Float16* __restrict__ tn, _Float16* __restrict__ qn, int N) {
    __shared__ _Float16 xl[16 * FEAT];
    int wv = threadIdx.x >> 6;
    int lane = threadIdx.x & 63;
    int g = lane >> 4;
    int c = lane & 15;
    int node0 = blockIdx.x * 16;

    // phase 1: each wave aggs 4 consecutive nodes
#pragma unroll 1
    for (int k = 0; k < 4; ++k) {
        int nr = wv * 4 + k;
        int node = node0 + nr;
        float o0 = 0.f, o1 = 0.f;
        if (node < N) {
            int bi = node * SLABS;
            int beg = row_ptr4[bi] + boff[bi >> 10];
            int end = row_ptr4[bi + SLABS] + boff[(bi + SLABS) >> 10];
            f16x2 qv = *(const f16x2*)(q16 + (size_t)node * FEAT + c * 8 + g * 2);
            f16x8 mm = gather_max(t16, esrc, beg, end - beg, lane, g, c);
            f16x2 mp = slot_pair(mm, g);
            o0 = fmaxf((float)mp[0] + (float)qv[0], 0.f);
            o1 = fmaxf((float)mp[1] + (float)qv[1], 0.f);
        }
        f16x2 oh; oh[0] = (_Float16)o0; oh[1] = (_Float16)o1;
        int byteoff = (nr * 256 + c * 16 + g * 4) ^ ((nr & 7) << 4);
        *(f16x2*)((char*)xl + byteoff) = oh;
    }
    __syncthreads();

    // phase 2: 16-row x 128-col double GEMM from LDS. Wave wv owns 32 cols.
    int l16 = lane & 15;
    int quad = lane >> 4;
    int cn0 = wv * 32;
    f16x8 a[4];
#pragma unroll
    for (int kk = 0; kk < 4; ++kk) {
        int byteoff = (l16 * 256 + kk * 64 + quad * 16) ^ ((l16 & 7) << 4);
        a[kk] = *(const f16x8*)((const char*)xl + byteoff);
    }
#pragma unroll 1
    for (int ct = 0; ct < 2; ++ct) {
        int col = cn0 + ct * 16 + l16;
        float bv = bias[col];
        f16x8 fb[4];
#pragma unroll
        for (int kk = 0; kk < 4; ++kk)
            fb[kk] = *(const f16x8*)(wt + (size_t)col * FEAT + kk * 32 + quad * 8);
        f32x4 accT = {0.f, 0.f, 0.f, 0.f};
#pragma unroll
        for (int kk = 0; kk < 4; ++kk)
            accT = __builtin_amdgcn_mfma_f32_16x16x32_f16(a[kk], fb[kk], accT, 0, 0, 0);
#pragma unroll
        for (int kk = 0; kk < 4; ++kk)
            fb[kk] = *(const f16x8*)(wp + (size_t)col * FEAT + kk * 32 + quad * 8);
        f32x4 accP = {0.f, 0.f, 0.f, 0.f};
#pragma unroll
        for (int kk = 0; kk < 4; ++kk)
            accP = __builtin_amdgcn_mfma_f32_16x16x32_f16(a[kk], fb[kk], accP, 0, 0, 0);
#pragma unroll
        for (int r = 0; r < 4; ++r) {
            int ro = node0 + quad * 4 + r;
            if (ro < N) {
                tn[(size_t)ro * FEAT + col] = (_Float16)accT[r];
                qn[(size_t)ro * FEAT + col] = (_Float16)(accP[r] - accT[r] + bv);
            }
        }
    }
}

// Final-layer agg: full-occupancy standalone, writes fp32 d_out.
__global__ __launch_bounds__(256) void agg_kernel(
        const _Float16* __restrict__ t16, const _Float16* __restrict__ q16,
        const int* __restrict__ row_ptr4, const int* __restrict__ boff,
        const int* __restrict__ esrc,
        float* __restrict__ outf, int N) {
    int wv = threadIdx.x >> 6;
    int lane = threadIdx.x & 63;
    int node = blockIdx.x * 4 + wv;
    if (node >= N) return;

    int g = lane >> 4;
    int c = lane & 15;

    int bi = node * SLABS;
    int beg = row_ptr4[bi] + boff[bi >> 10];
    int end = row_ptr4[bi + SLABS] + boff[(bi + SLABS) >> 10];

    f16x2 qv = *(const f16x2*)(q16 + (size_t)node * FEAT + c * 8 + g * 2);
    f16x8 mm = gather_max(t16, esrc, beg, end - beg, lane, g, c);
    f16x2 mp = slot_pair(mm, g);

    float o0 = fmaxf((float)mp[0] + (float)qv[0], 0.f);
    float o1 = fmaxf((float)mp[1] + (float)qv[1], 0.f);
    float2 ov = make_float2(o0, o1);
    *(float2*)(outf + (size_t)node * FEAT + c * 8 + g * 2) = ov;
}

// ---------------------------------------------------------------------------

extern "C" void kernel_launch(void* const* d_in, const int* in_sizes, int n_in,
                              void* d_out, int out_size, void* d_ws, size_t ws_size,
                              hipStream_t stream) {
    const float* feats   = (const float*)d_in[0];
    const int*   src     = (const int*)d_in[1];
    const int*   dst     = (const int*)d_in[2];
    const float* theta_w = (const float*)d_in[3];
    const float* theta_b = (const float*)d_in[4];
    const float* phi_w   = (const float*)d_in[5];
    const float* phi_b   = (const float*)d_in[6];

    const int N = in_sizes[0] / FEAT;
    const int E = in_sizes[1];
    const int L = in_sizes[3] / (FEAT * FEAT);
    const int N4 = N * SLABS;
    const int slab_size = (N + SLABS - 1) / SLABS;

    char* ws = (char*)d_ws;
    size_t off = 0;
    auto alloc = [&](size_t bytes) -> void* {
        void* ptr = ws + off;
        off = (off + bytes + 255) & ~(size_t)255;
        return ptr;
    };
    _Float16* tbuf[2];
    _Float16* qbuf[2];
    tbuf[0] = (_Float16*)alloc((size_t)N * FEAT * 2);
    tbuf[1] = (_Float16*)alloc((size_t)N * FEAT * 2);
    qbuf[0] = (_Float16*)alloc((size_t)N * FEAT * 2);
    qbuf[1] = (_Float16*)alloc((size_t)N * FEAT * 2);
    _Float16* x16 = (_Float16*)alloc((size_t)N * FEAT * 2);
    _Float16* wt16 = (_Float16*)alloc((size_t)L * FEAT * FEAT * 2);
    _Float16* wp16 = (_Float16*)alloc((size_t)L * FEAT * FEAT * 2);
    float* bsum_b = (float*)alloc((size_t)L * FEAT * sizeof(float));
    int* deg4     = (int*)alloc((size_t)N4 * sizeof(int));
    int* row_ptr4 = (int*)alloc((size_t)(N4 + 1) * sizeof(int));
    int* erank    = (int*)alloc((size_t)E * sizeof(int));
    int* esrc     = (int*)alloc((size_t)E * sizeof(int));
    int* bsum     = (int*)alloc(2048 * sizeof(int));
    int* boff     = (int*)alloc(2048 * sizeof(int));
    (void)ws_size;

    hipMemsetAsync(deg4, 0, (size_t)N4 * sizeof(int), stream);

    int eb = (E + 255) / 256;
    int wn = L * FEAT * FEAT;
    int wb = (wn + 255) / 256;
    int xn4 = N * FEAT / 4;
    int xb = (xn4 + 255) / 256;
    prep_kernel<<<eb + wb + xb, 256, 0, stream>>>(
        src, dst, deg4, erank, E, slab_size,
        theta_w, phi_w, theta_b, phi_b, wt16, wp16, bsum_b, wn, L * FEAT,
        feats, x16, xn4, eb, wb);

    int nb = (N4 + 1023) >> 10;
    scan1_kernel<<<nb, 1024, 0, stream>>>(deg4, row_ptr4, bsum, N4);
    scan2_kernel<<<1, 1024, 0, stream>>>(bsum, boff, row_ptr4, nb, N4, E);

    int gb = (N + 127) / 128;
    fused0_kernel<<<gb + eb, 256, 0, stream>>>(
        x16, wt16, wp16, bsum_b, tbuf[0], qbuf[0], N, gb,
        src, dst, row_ptr4, boff, erank, esrc, E, slab_size);

    int fb = (N + 15) / 16;   // fusedagg: 16 nodes/block (r8 config)
    for (int l = 0; l + 1 < L; ++l) {
        fusedagg_kernel<<<fb, 256, 0, stream>>>(
            tbuf[l & 1], qbuf[l & 1], row_ptr4, boff, esrc,
            wt16 + (size_t)(l + 1) * FEAT * FEAT,
            wp16 + (size_t)(l + 1) * FEAT * FEAT,
            bsum_b + (size_t)(l + 1) * FEAT,
            tbuf[(l + 1) & 1], qbuf[(l + 1) & 1], N);
    }

    int ab = (N + 3) / 4;
    agg_kernel<<<ab, 256, 0, stream>>>(
        tbuf[(L - 1) & 1], qbuf[(L - 1) & 1], row_ptr4, boff, esrc,
        (float*)d_out, N);
}

// Round 13
// 301.771 us; speedup vs baseline: 1.0776x; 1.0305x over previous
//
#include <hip/hip_runtime.h>

#define FEAT 128
#define SLABS 4

typedef __attribute__((ext_vector_type(8))) _Float16 f16x8;
typedef __attribute__((ext_vector_type(2))) _Float16 f16x2;
typedef __attribute__((ext_vector_type(4))) float f32x4;

static __device__ __forceinline__ int wave_incl_scan(int v, int lane) {
#pragma unroll
    for (int off = 1; off < 64; off <<= 1) {
        int u = __shfl_up(v, off, 64);
        if (lane >= off) v += u;
    }
    return v;
}

// ---------------------------------------------------------------------------
// Prep: histogram over (dst,slab) keys + weight/bias/feat converts, one
// dispatch partitioned by blockIdx. atomicAdd return = edge rank in bucket
// -> erank (atomic-free scatter later). SLABS=4 kept (r10: removing it cost
// gather locality + 4x histogram contention, net -14 us).
// ---------------------------------------------------------------------------

__global__ void prep_kernel(const int* __restrict__ src, const int* __restrict__ dst,
                            int* __restrict__ deg4, int* __restrict__ erank,
                            int E, int slab_size,
                            const float* __restrict__ tw, const float* __restrict__ pw,
                            const float* __restrict__ tb, const float* __restrict__ pb,
                            _Float16* __restrict__ wt, _Float16* __restrict__ wp,
                            float* __restrict__ bsum, int wn, int nbias,
                            const float* __restrict__ x, _Float16* __restrict__ x16, int xn4,
                            int hb, int wb) {
    int bid = blockIdx.x;
    if (bid < hb) {
        int e = bid * 256 + threadIdx.x;
        if (e < E) {
            int sl = src[e] / slab_size;
            erank[e] = atomicAdd(&deg4[dst[e] * SLABS + sl], 1);
        }
    } else if (bid < hb + wb) {
        int i = (bid - hb) * 256 + threadIdx.x;
        if (i < wn) { wt[i] = (_Float16)tw[i]; wp[i] = (_Float16)pw[i]; }
        if (i < nbias) bsum[i] = tb[i] + pb[i];
    } else {
        int i = (bid - hb - wb) * 256 + threadIdx.x;
        if (i < xn4) {
            float4 v = ((const float4*)x)[i];
            f16x2 a, b;
            a[0] = (_Float16)v.x; a[1] = (_Float16)v.y;
            b[0] = (_Float16)v.z; b[1] = (_Float16)v.w;
            ((f16x2*)x16)[i * 2] = a;
            ((f16x2*)x16)[i * 2 + 1] = b;
        }
    }
}

// ---------------------------------------------------------------------------
// 2-dispatch scan (scan3 folded into consumers: they add boff[idx>>10]).
// Round-5 lesson: NO single-dispatch device-scope-spin scan (cost 103 us).
// ---------------------------------------------------------------------------

__global__ __launch_bounds__(1024) void scan1_kernel(const int* __restrict__ deg,
                                                     int* __restrict__ row_ptr,
                                                     int* __restrict__ bsum, int N4) {
    int i = blockIdx.x * 1024 + threadIdx.x;
    int lane = threadIdx.x & 63;
    int w = threadIdx.x >> 6;
    int v = (i < N4) ? deg[i] : 0;
    int inc = wave_incl_scan(v, lane);
    __shared__ int wsum[16];
    if (lane == 63) wsum[w] = inc;
    __syncthreads();
    if (w == 0) {
        int s = (lane < 16) ? wsum[lane] : 0;
        int si = wave_incl_scan(s, lane);
        if (lane < 16) wsum[lane] = si - s;
    }
    __syncthreads();
    int exc = inc - v + wsum[w];
    if (i < N4) row_ptr[i] = exc;
    if (threadIdx.x == 1023) bsum[blockIdx.x] = exc + v;
}

// boff[tid] for tid<=nb; sentinel row_ptr[N4] pre-compensated so that
// consumers can uniformly compute row_ptr[idx] + boff[idx>>10].
__global__ __launch_bounds__(1024) void scan2_kernel(const int* __restrict__ bsum,
                                                     int* __restrict__ boff,
                                                     int* __restrict__ row_ptr,
                                                     int nb, int N4, int E) {
    int tid = threadIdx.x;
    int lane = tid & 63;
    int w = tid >> 6;
    int v = (tid < nb) ? bsum[tid] : 0;
    int inc = wave_incl_scan(v, lane);
    __shared__ int wsum[16];
    if (lane == 63) wsum[w] = inc;
    __syncthreads();
    if (w == 0) {
        int s = (lane < 16) ? wsum[lane] : 0;
        int si = wave_incl_scan(s, lane);
        if (lane < 16) wsum[lane] = si - s;
    }
    __syncthreads();
    int b = inc - v + wsum[w];
    if (tid <= nb) boff[tid] = b;
    if (tid == (N4 >> 10)) row_ptr[N4] = E - b;   // + boff[N4>>10] == E
}

// ---------------------------------------------------------------------------
// Fused MFMA GEMM body (verified): t = x @ Wt.T, q = x @ Wp.T - t + (tb+pb).
// C/D layout: col = lane&15, row = (lane>>4)*4+reg.
// ---------------------------------------------------------------------------

static __device__ __forceinline__ void gemm_body(
        int bx, int nslab,
        const _Float16* __restrict__ x16,
        const _Float16* __restrict__ wt, const _Float16* __restrict__ wp,
        const float* __restrict__ bias,
        _Float16* __restrict__ t16, _Float16* __restrict__ q16, int M) {
    int lane = threadIdx.x & 63;
    int l16 = lane & 15;
    int quad = lane >> 4;
    int cn0 = (threadIdx.x >> 6) * 32;

    f16x8 bt[2][4], bp[2][4];
    float biasv[2];
#pragma unroll
    for (int ct = 0; ct < 2; ++ct) {
        int col = cn0 + ct * 16 + l16;
        biasv[ct] = bias[col];
#pragma unroll
        for (int kk = 0; kk < 4; ++kk) {
            int k = kk * 32 + quad * 8;
            bt[ct][kk] = *(const f16x8*)(wt + (size_t)col * FEAT + k);
            bp[ct][kk] = *(const f16x8*)(wp + (size_t)col * FEAT + k);
        }
    }

    int rbase0 = bx * (nslab * 16);
#pragma unroll 1
    for (int rs = 0; rs < nslab; ++rs) {
        int rbase = rbase0 + rs * 16;
        int row = rbase + l16;
        int rowc = (row < M) ? row : (M - 1);
        f16x8 a[4];
#pragma unroll
        for (int kk = 0; kk < 4; ++kk)
            a[kk] = *(const f16x8*)(x16 + (size_t)rowc * FEAT + kk * 32 + quad * 8);

        f32x4 accT[2] = {{0.f, 0.f, 0.f, 0.f}, {0.f, 0.f, 0.f, 0.f}};
        f32x4 accP[2] = {{0.f, 0.f, 0.f, 0.f}, {0.f, 0.f, 0.f, 0.f}};
#pragma unroll
        for (int kk = 0; kk < 4; ++kk) {
#pragma unroll
            for (int ct = 0; ct < 2; ++ct) {
                accT[ct] = __builtin_amdgcn_mfma_f32_16x16x32_f16(a[kk], bt[ct][kk], accT[ct], 0, 0, 0);
                accP[ct] = __builtin_amdgcn_mfma_f32_16x16x32_f16(a[kk], bp[ct][kk], accP[ct], 0, 0, 0);
            }
        }
#pragma unroll
        for (int ct = 0; ct < 2; ++ct) {
            int col = cn0 + ct * 16 + l16;
#pragma unroll
            for (int r = 0; r < 4; ++r) {
                int ro = rbase + quad * 4 + r;
                if (ro < M) {
                    t16[(size_t)ro * FEAT + col] = (_Float16)accT[ct][r];
                    q16[(size_t)ro * FEAT + col] =
                        (_Float16)(accP[ct][r] - accT[ct][r] + biasv[ct]);
                }
            }
        }
    }
}

// Layer-0 GEMM fused with the atomic-free CSR scatter.
__global__ __launch_bounds__(256) void fused0_kernel(
        const _Float16* __restrict__ x16,
        const _Float16* __restrict__ wt, const _Float16* __restrict__ wp,
        const float* __restrict__ bias,
        _Float16* __restrict__ t16, _Float16* __restrict__ q16, int M, int gb,
        const int* __restrict__ src, const int* __restrict__ dst,
        const int* __restrict__ row_ptr4, const int* __restrict__ boff,
        const int* __restrict__ erank,
        int* __restrict__ esrc, int E, int slab_size) {
    if ((int)blockIdx.x < gb) {
        gemm_body(blockIdx.x, 8, x16, wt, wp, bias, t16, q16, M);
    } else {
        int e = (blockIdx.x - gb) * 256 + threadIdx.x;
        if (e < E) {
            int s = src[e];
            int key = dst[e] * SLABS + s / slab_size;
            esrc[row_ptr4[key] + boff[key >> 10] + erank[e]] = s;
        }
    }
}

// ---------------------------------------------------------------------------
// Gather-max core. vmax8 = v_pk_max_f16 x4 (r12: cut VALUBusy 46->31%, dur
// unchanged -> gather is miss-concurrency-bound, not VALU-bound). Gather
// structure at its request floor (insensitive r1/r3/r4/r8/r9/r10/r12) --
// do not restructure. This round attacks the per-node STARTUP chains via
// cross-node prefetch (see fusedagg).
// ---------------------------------------------------------------------------

static __device__ __forceinline__ f16x8 vmax8(f16x8 a, f16x8 b) {
    return __builtin_elementwise_max(a, b);
}

static __device__ __forceinline__ f16x8 shfl_xor8(f16x8 v, int m) {
    union { f16x8 h; int i[4]; } u, r;
    u.h = v;
#pragma unroll
    for (int d = 0; d < 4; ++d) r.i[d] = __shfl_xor(u.i[d], m, 64);
    return r.h;
}

// Core loop with the FIRST index chunk preloaded (myidx); later chunks
// reload in-loop as before.
static __device__ __forceinline__ f16x8 gather_max_pre(
        const _Float16* __restrict__ t16, const int* __restrict__ esrc,
        int beg, int cnt, int myidx, int lane, int g, int c) {
    const _Float16 NEGINF = (_Float16)(-65504.0f);
    f16x8 m0, m1;
#pragma unroll
    for (int i = 0; i < 8; ++i) { m0[i] = NEGINF; m1[i] = NEGINF; }

    for (int cb = 0; cb < cnt; cb += 64) {
        int lim = cnt - cb; if (lim > 64) lim = 64;
        if (cb > 0) {
            int a = beg + cb + (lane < lim ? lane : 0);
            myidx = esrc[a];
        }
        for (int base = 0; base < lim; base += 8) {
            int e0 = base + g;     if (e0 >= lim) e0 = 0;
            int e1 = base + 4 + g; if (e1 >= lim) e1 = 0;
            int i0 = __shfl(myidx, e0, 64);
            int i1 = __shfl(myidx, e1, 64);
            f16x8 v0 = *(const f16x8*)(t16 + (size_t)i0 * FEAT + c * 8);
            f16x8 v1 = *(const f16x8*)(t16 + (size_t)i1 * FEAT + c * 8);
            m0 = vmax8(m0, v0);
            m1 = vmax8(m1, v1);
        }
    }

    f16x8 mm = vmax8(m0, m1);
    mm = vmax8(mm, shfl_xor8(mm, 16));
    mm = vmax8(mm, shfl_xor8(mm, 32));
    return mm;
}

// lane (g,c) owns features {c*8+2g, c*8+2g+1}: static select of dword g.
static __device__ __forceinline__ f16x2 slot_pair(f16x8 mm, int g) {
    union { f16x8 h; int i[4]; } um; um.h = mm;
    int w01 = (g & 1) ? um.i[1] : um.i[0];
    int w23 = (g & 1) ? um.i[3] : um.i[2];
    int w = (g & 2) ? w23 : w01;
    union { int i; f16x2 h; } uw; uw.i = w;
    return uw.h;
}

// ---------------------------------------------------------------------------
// Fused agg(layer l) + GEMM(layer l+1), 256 thr / 4 waves, 4 nodes per wave
// (r8 verified config). NEW: cross-node startup prefetch -- one coalesced
// 17-lane row_ptr4 load gives all 4 nodes' beg/end; all 4 first-chunk esrc
// loads + all 4 q16 loads issue back-to-back BEFORE any gather, overlapping
// ~2-3k cycles/wave of previously-serial dependent-load latency (the r8
// k-loop ran 4 strictly sequential chains: row_ptr -> esrc -> shfl ->
// gather). k-loop fully unrolled so all per-node state is static-indexed
// (no scratch). x_next passes through the 4 KB XOR-swizzled LDS tile;
// phase 2 = 16-row double-GEMM. t/q double-buffered across layers.
// ---------------------------------------------------------------------------

__global__ __launch_bounds__(256) void fusedagg_kernel(
        const _Float16* __restrict__ t16, const _Float16* __restrict__ q16,
        const int* __restrict__ row_ptr4, const int* __restrict__ boff,
        const int* __restrict__ esrc,
        const _Float16* __restrict__ wt, const _Float16* __restrict__ wp,
        const float* __restrict__ bias,
        _Float16* __restrict__ tn, _Float16* __restrict__ qn, int N) {
    __shared__ _Float16 xl[16 * FEAT];
    int wv = threadIdx.x >> 6;
    int lane = threadIdx.x & 63;
    int g = lane >> 4;
    int c = lane & 15;
    int node0 = blockIdx.x * 16;
    int N4 = N * SLABS;

    // ---- startup prefetch (all independent loads issue back-to-back) ----
    // 17 consecutive row_ptr4 entries cover this wave's 4 nodes' boundaries.
    int bi0 = (node0 + wv * 4) * SLABS;
    int rpidx = bi0 + (lane < 17 ? lane : 16);
    if (rpidx > N4) rpidx = N4;
    int rpb = row_ptr4[rpidx] + boff[rpidx >> 10];

    int beg[4], cnt[4], myidx[4];
    f16x2 qv[4];
#pragma unroll
    for (int k = 0; k < 4; ++k) {
        int b = __shfl(rpb, 4 * k, 64);
        int e = __shfl(rpb, 4 * k + 4, 64);
        beg[k] = b;
        cnt[k] = e - b;
        int cl = cnt[k] < 64 ? cnt[k] : 64;
        int a = b + (lane < cl ? lane : 0);
        myidx[k] = (cnt[k] > 0) ? esrc[a] : 0;
        int node = node0 + wv * 4 + k;
        if (node < N)
            qv[k] = *(const f16x2*)(q16 + (size_t)node * FEAT + c * 8 + g * 2);
        else { qv[k][0] = (_Float16)0.f; qv[k][1] = (_Float16)0.f; }
    }

    // ---- phase 1: gather-max per node (fully unrolled, static indices) ----
#pragma unroll
    for (int k = 0; k < 4; ++k) {
        int nr = wv * 4 + k;
        int node = node0 + nr;
        float o0 = 0.f, o1 = 0.f;
        if (node < N) {
            f16x8 mm = gather_max_pre(t16, esrc, beg[k], cnt[k], myidx[k], lane, g, c);
            f16x2 mp = slot_pair(mm, g);
            o0 = fmaxf((float)mp[0] + (float)qv[k][0], 0.f);
            o1 = fmaxf((float)mp[1] + (float)qv[k][1], 0.f);
        }
        f16x2 oh; oh[0] = (_Float16)o0; oh[1] = (_Float16)o1;
        int byteoff = (nr * 256 + c * 16 + g * 4) ^ ((nr & 7) << 4);
        *(f16x2*)((char*)xl + byteoff) = oh;
    }
    __syncthreads();

    // ---- phase 2: 16-row x 128-col double GEMM from LDS ----
    int l16 = lane & 15;
    int quad = lane >> 4;
    int cn0 = wv * 32;
    f16x8 a[4];
#pragma unroll
    for (int kk = 0; kk < 4; ++kk) {
        int byteoff = (l16 * 256 + kk * 64 + quad * 16) ^ ((l16 & 7) << 4);
        a[kk] = *(const f16x8*)((const char*)xl + byteoff);
    }
#pragma unroll 1
    for (int ct = 0; ct < 2; ++ct) {
        int col = cn0 + ct * 16 + l16;
        float bv = bias[col];
        f16x8 fb[4];
#pragma unroll
        for (int kk = 0; kk < 4; ++kk)
            fb[kk] = *(const f16x8*)(wt + (size_t)col * FEAT + kk * 32 + quad * 8);
        f32x4 accT = {0.f, 0.f, 0.f, 0.f};
#pragma unroll
        for (int kk = 0; kk < 4; ++kk)
            accT = __builtin_amdgcn_mfma_f32_16x16x32_f16(a[kk], fb[kk], accT, 0, 0, 0);
#pragma unroll
        for (int kk = 0; kk < 4; ++kk)
            fb[kk] = *(const f16x8*)(wp + (size_t)col * FEAT + kk * 32 + quad * 8);
        f32x4 accP = {0.f, 0.f, 0.f, 0.f};
#pragma unroll
        for (int kk = 0; kk < 4; ++kk)
            accP = __builtin_amdgcn_mfma_f32_16x16x32_f16(a[kk], fb[kk], accP, 0, 0, 0);
#pragma unroll
        for (int r = 0; r < 4; ++r) {
            int ro = node0 + quad * 4 + r;
            if (ro < N) {
                tn[(size_t)ro * FEAT + col] = (_Float16)accT[r];
                qn[(size_t)ro * FEAT + col] = (_Float16)(accP[r] - accT[r] + bv);
            }
        }
    }
}

// Final-layer agg: full-occupancy standalone, writes fp32 d_out.
__global__ __launch_bounds__(256) void agg_kernel(
        const _Float16* __restrict__ t16, const _Float16* __restrict__ q16,
        const int* __restrict__ row_ptr4, const int* __restrict__ boff,
        const int* __restrict__ esrc,
        float* __restrict__ outf, int N) {
    int wv = threadIdx.x >> 6;
    int lane = threadIdx.x & 63;
    int node = blockIdx.x * 4 + wv;
    if (node >= N) return;

    int g = lane >> 4;
    int c = lane & 15;

    int bi = node * SLABS;
    int beg = row_ptr4[bi] + boff[bi >> 10];
    int end = row_ptr4[bi + SLABS] + boff[(bi + SLABS) >> 10];
    int cnt = end - beg;

    f16x2 qv = *(const f16x2*)(q16 + (size_t)node * FEAT + c * 8 + g * 2);
    int cl = cnt < 64 ? cnt : 64;
    int a0 = beg + (lane < cl ? lane : 0);
    int my0 = (cnt > 0) ? esrc[a0] : 0;
    f16x8 mm = gather_max_pre(t16, esrc, beg, cnt, my0, lane, g, c);
    f16x2 mp = slot_pair(mm, g);

    float o0 = fmaxf((float)mp[0] + (float)qv[0], 0.f);
    float o1 = fmaxf((float)mp[1] + (float)qv[1], 0.f);
    float2 ov = make_float2(o0, o1);
    *(float2*)(outf + (size_t)node * FEAT + c * 8 + g * 2) = ov;
}

// ---------------------------------------------------------------------------

extern "C" void kernel_launch(void* const* d_in, const int* in_sizes, int n_in,
                              void* d_out, int out_size, void* d_ws, size_t ws_size,
                              hipStream_t stream) {
    const float* feats   = (const float*)d_in[0];
    const int*   src     = (const int*)d_in[1];
    const int*   dst     = (const int*)d_in[2];
    const float* theta_w = (const float*)d_in[3];
    const float* theta_b = (const float*)d_in[4];
    const float* phi_w   = (const float*)d_in[5];
    const float* phi_b   = (const float*)d_in[6];

    const int N = in_sizes[0] / FEAT;
    const int E = in_sizes[1];
    const int L = in_sizes[3] / (FEAT * FEAT);
    const int N4 = N * SLABS;
    const int slab_size = (N + SLABS - 1) / SLABS;

    char* ws = (char*)d_ws;
    size_t off = 0;
    auto alloc = [&](size_t bytes) -> void* {
        void* ptr = ws + off;
        off = (off + bytes + 255) & ~(size_t)255;
        return ptr;
    };
    _Float16* tbuf[2];
    _Float16* qbuf[2];
    tbuf[0] = (_Float16*)alloc((size_t)N * FEAT * 2);
    tbuf[1] = (_Float16*)alloc((size_t)N * FEAT * 2);
    qbuf[0] = (_Float16*)alloc((size_t)N * FEAT * 2);
    qbuf[1] = (_Float16*)alloc((size_t)N * FEAT * 2);
    _Float16* x16 = (_Float16*)alloc((size_t)N * FEAT * 2);
    _Float16* wt16 = (_Float16*)alloc((size_t)L * FEAT * FEAT * 2);
    _Float16* wp16 = (_Float16*)alloc((size_t)L * FEAT * FEAT * 2);
    float* bsum_b = (float*)alloc((size_t)L * FEAT * sizeof(float));
    int* deg4     = (int*)alloc((size_t)N4 * sizeof(int));
    int* row_ptr4 = (int*)alloc((size_t)(N4 + 1) * sizeof(int));
    int* erank    = (int*)alloc((size_t)E * sizeof(int));
    int* esrc     = (int*)alloc((size_t)E * sizeof(int));
    int* bsum     = (int*)alloc(2048 * sizeof(int));
    int* boff     = (int*)alloc(2048 * sizeof(int));
    (void)ws_size;

    hipMemsetAsync(deg4, 0, (size_t)N4 * sizeof(int), stream);

    int eb = (E + 255) / 256;
    int wn = L * FEAT * FEAT;
    int wb = (wn + 255) / 256;
    int xn4 = N * FEAT / 4;
    int xb = (xn4 + 255) / 256;
    prep_kernel<<<eb + wb + xb, 256, 0, stream>>>(
        src, dst, deg4, erank, E, slab_size,
        theta_w, phi_w, theta_b, phi_b, wt16, wp16, bsum_b, wn, L * FEAT,
        feats, x16, xn4, eb, wb);

    int nb = (N4 + 1023) >> 10;
    scan1_kernel<<<nb, 1024, 0, stream>>>(deg4, row_ptr4, bsum, N4);
    scan2_kernel<<<1, 1024, 0, stream>>>(bsum, boff, row_ptr4, nb, N4, E);

    int gb = (N + 127) / 128;
    fused0_kernel<<<gb + eb, 256, 0, stream>>>(
        x16, wt16, wp16, bsum_b, tbuf[0], qbuf[0], N, gb,
        src, dst, row_ptr4, boff, erank, esrc, E, slab_size);

    int fb = (N + 15) / 16;   // fusedagg: 16 nodes/block (r8 config + prefetch)
    for (int l = 0; l + 1 < L; ++l) {
        fusedagg_kernel<<<fb, 256, 0, stream>>>(
            tbuf[l & 1], qbuf[l & 1], row_ptr4, boff, esrc,
            wt16 + (size_t)(l + 1) * FEAT * FEAT,
            wp16 + (size_t)(l + 1) * FEAT * FEAT,
            bsum_b + (size_t)(l + 1) * FEAT,
            tbuf[(l + 1) & 1], qbuf[(l + 1) & 1], N);
    }

    int ab = (N + 3) / 4;
    agg_kernel<<<ab, 256, 0, stream>>>(
        tbuf[(L - 1) & 1], qbuf[(L - 1) & 1], row_ptr4, boff, esrc,
        (float*)d_out, N);
}